// Round 11
// baseline (1440.402 us; speedup 1.0000x reference)
//
#include <hip/hip_runtime.h>
#include <stdint.h>

// FastRNN: B=64, T=512, I=256, H=512, fp32.
// R17: K1 (wx GEMM) FUSED into the scan, overlapped with the exchange wait.
//   Evidence: R14/R15/R16 bracket 1076-1088us — K2's load-order lever is
//   exhausted; but total-vs-rnn gap = ~115us of wx_gemm+launch, and the
//   head spin is pure idle. x_t@W is poll-INDEPENDENT -> compute it at the
//   head, before the tag check, inside the exchange-latency window:
//   - Wf[2][8] register-resident (Uf pattern); x staged in xls[2][16][264]
//     LDS dbuf: 4 contiguous float4/thread (plain loads; LLC dedupes the
//     4x s-slice sharing), f2bf -> LDS post-C (write-window safe: last
//     reader of xls[1-p] finished before t-1's F), consumed at t+1 head.
//   - Head: 16 x-MFMAs (accX) -> sched_barrier(0) -> R14's exact spin ->
//     C -> partner MFMA with acc = accO + accX -> epilogue adds bias ->
//     F -> R14's exact tail. wxb workspace + K1 dispatch deleted.
//   Protocol (poll/publish/tags/barriers/split-accumulation) = R14 verbatim.
// R14 structure: 16 blocks = 4 batch-groups x 4 j-slices, 256 thr; own 4
//   h-ktiles computed in the post-publish window; 12KB partner poll; proven
//   __hip_atomic relaxed-agent exchange; 2 barriers/step (+1 pre-loop).

#define B_ 64
#define T_ 512
#define I_ 256
#define H_ 512

#define HHALF_BYTES ((size_t)B_ * H_ * 2)      // 64 KiB bf16 per parity

typedef short v8s __attribute__((ext_vector_type(8)));
typedef float v4f __attribute__((ext_vector_type(4)));
typedef unsigned long long u64t;

__device__ __forceinline__ uint16_t f2bf(float x) {
    union { float f; uint32_t u; } v; v.f = x;
    return (uint16_t)((v.u + 0x7FFFu + ((v.u >> 16) & 1u)) >> 16);
}

// --------------- fused recurrent scan --------------------------------------
__global__ __launch_bounds__(256, 1) void rnn_scan(
        const float* __restrict__ x, const float* __restrict__ W,
        const float* __restrict__ U, const float* __restrict__ bias,
        const float* __restrict__ alpha, const float* __restrict__ beta,
        float* __restrict__ out, uint16_t* __restrict__ Hbuf) {
    __shared__ __align__(16) uint16_t Als[2][16][520];  // dbuf h state, +8 pad
    __shared__ __align__(16) uint16_t xls[2][16][264];  // dbuf x_t bf16, +8 pad

    const int bid = blockIdx.x;       // 0..15
    const int g = bid >> 2, s = bid & 3;
    const int tid = threadIdx.x;      // 0..255
    const int lane = tid & 63;
    const int w = tid >> 6;           // wave 0..3
    const int q = lane >> 4, c = lane & 15;

    float sa, sb;
    { float a = alpha[0], b = beta[0];
      sa = 1.f / (1.f + __expf(-a)); sb = 1.f / (1.f + __expf(-b)); }

    // Loop-invariant U B-frags, [12 partner ktiles | 4 own ktiles] (R14).
    v8s Uf[2][16];
    #pragma unroll
    for (int nt = 0; nt < 2; ++nt) {
        int jg = s * 128 + (2 * w + nt) * 16 + c;
        #pragma unroll
        for (int slot = 0; slot < 16; ++slot) {
            int ktile = (slot < 12) ? (slot + ((slot >= (s << 2)) ? 4 : 0))
                                    : ((s << 2) + slot - 12);
            const float* gp = U + (size_t)(ktile * 32 + q * 8) * H_ + jg;
            union { v8s v; uint16_t u[8]; } pk;
            #pragma unroll
            for (int jj = 0; jj < 8; ++jj) pk.u[jj] = f2bf(gp[(size_t)jj * H_]);
            Uf[nt][slot] = pk.v;
        }
    }
    // Loop-invariant W B-frags (I=256 -> 8 ktiles), same fragment pattern.
    v8s Wf[2][8];
    #pragma unroll
    for (int nt = 0; nt < 2; ++nt) {
        int jg = s * 128 + (2 * w + nt) * 16 + c;
        #pragma unroll
        for (int kt = 0; kt < 8; ++kt) {
            const float* gp = W + (size_t)(kt * 32 + q * 8) * H_ + jg;
            union { v8s v; uint16_t u[8]; } pk;
            #pragma unroll
            for (int jj = 0; jj < 8; ++jj) pk.u[jj] = f2bf(gp[(size_t)jj * H_]);
            Wf[nt][kt] = pk.v;
        }
    }
    // bias (was added by K1; now in the epilogue).
    float bias_r[2];
    #pragma unroll
    for (int nt = 0; nt < 2; ++nt)
        bias_r[nt] = bias[s * 128 + (2 * w + nt) * 16 + c];

    float hold[2][4];
    #pragma unroll
    for (int nt = 0; nt < 2; ++nt)
        #pragma unroll
        for (int r = 0; r < 4; ++r) hold[nt][r] = 0.f;

    // Partner poll mapping (R14): 3 partner slices, 16B chunk per thread.
    const int prow = tid >> 4;
    size_t poffv[3];
    int pcolv[3];
    #pragma unroll
    for (int i = 0; i < 3; ++i) {
        int sp = i + ((i >= s) ? 1 : 0);
        pcolv[i] = sp * 128 + (tid & 15) * 8;
        poffv[i] = ((size_t)(g * 16 + prow)) * H_ + pcolv[i];
    }
    // Publish mapping (R14).
    const int orow = tid >> 4;
    const int ocol = s * 128 + (tid & 15) * 8;
    const size_t ooff = ((size_t)(g * 16 + orow)) * H_ + ocol;

    // Zero ALL of Als[0] (h_0 = 0): 2048 u64s, 8 per thread (R14-fixed).
    #pragma unroll
    for (int u = 0; u < 8; ++u)
        *((u64t*)&Als[0][tid >> 4][0] + (tid & 15) * 8 + u) = 0;

    // x staging geometry: thread owns row r0 = tid>>4 (batch g*16+r0),
    // cols c16..c16+15 (64B contiguous -> 4 float4 loads).
    const int r0 = tid >> 4, c16 = (tid & 15) * 16;
    // Stage xls[0] = x(t=0).
    {
        const float* gx = x + ((size_t)(g * 16 + r0) * T_ + 0) * I_ + c16;
        float4 f0 = *(const float4*)(gx + 0);
        float4 f1 = *(const float4*)(gx + 4);
        float4 f2 = *(const float4*)(gx + 8);
        float4 f3 = *(const float4*)(gx + 12);
        uint16_t* dp = &xls[0][r0][c16];
        dp[0] = f2bf(f0.x); dp[1] = f2bf(f0.y); dp[2]  = f2bf(f0.z); dp[3]  = f2bf(f0.w);
        dp[4] = f2bf(f1.x); dp[5] = f2bf(f1.y); dp[6]  = f2bf(f1.z); dp[7]  = f2bf(f1.w);
        dp[8] = f2bf(f2.x); dp[9] = f2bf(f2.y); dp[10] = f2bf(f2.z); dp[11] = f2bf(f2.w);
        dp[12] = f2bf(f3.x); dp[13] = f2bf(f3.y); dp[14] = f2bf(f3.z); dp[15] = f2bf(f3.w);
    }
    // xr = x(1); running pointer then aims at x(2).
    const float* xptr = x + ((size_t)(g * 16 + r0) * T_ + 1) * I_ + c16;
    float4 xr0 = *(const float4*)(xptr + 0);
    float4 xr1 = *(const float4*)(xptr + 4);
    float4 xr2 = *(const float4*)(xptr + 8);
    float4 xr3 = *(const float4*)(xptr + 12);
    xptr += I_;

    u64t ev[3][2];                 // early-issued partner poll loads
    v4f accO0 = (v4f){0.f, 0.f, 0.f, 0.f};   // own-ktile h contribution
    v4f accO1 = (v4f){0.f, 0.f, 0.f, 0.f};

    __syncthreads();   // pre-loop: Als[0] zeroing + xls[0] visible to all

    for (int t = 0; t < T_; ++t) {
        const int p = t & 1;

        // ---- HEAD: x_t @ W (poll-independent) — runs INSIDE the exchange
        //      wait window, before the tag check ----
        v4f accX0 = (v4f){0.f, 0.f, 0.f, 0.f};
        v4f accX1 = (v4f){0.f, 0.f, 0.f, 0.f};
        #pragma unroll
        for (int kt = 0; kt < 8; ++kt) {
            v8s a = *(const v8s*)((const uint16_t*)&xls[p][c][0] + kt * 32 + q * 8);
            accX0 = __builtin_amdgcn_mfma_f32_16x16x32_bf16(a, Wf[0][kt], accX0, 0, 0, 0);
            accX1 = __builtin_amdgcn_mfma_f32_16x16x32_bf16(a, Wf[1][kt], accX1, 0, 0, 0);
        }
        __builtin_amdgcn_sched_barrier(0);  // keep x-MFMAs ahead of the spin

        // ---- poll 3 partner slices into Als[p] (R14 exact) ----
        if (t > 0) {
            const uint16_t* hbp = Hbuf + (size_t)p * (B_ * H_);
            const u64t lsb = 0x0001000100010001ull;
            const u64t want = ((t >> 1) & 1) ? lsb : 0ull;
            for (int guard = 0; guard < (1 << 20); ++guard) {
                u64t xx = (ev[0][0] ^ want) | (ev[0][1] ^ want)
                        | (ev[1][0] ^ want) | (ev[1][1] ^ want)
                        | (ev[2][0] ^ want) | (ev[2][1] ^ want);
                if (!(xx & lsb)) break;
                #pragma unroll
                for (int i = 0; i < 3; ++i) {
                    const u64t* gp = (const u64t*)(hbp + poffv[i]);
                    ev[i][0] = __hip_atomic_load(&gp[0], __ATOMIC_RELAXED,
                                                 __HIP_MEMORY_SCOPE_AGENT);
                    ev[i][1] = __hip_atomic_load(&gp[1], __ATOMIC_RELAXED,
                                                 __HIP_MEMORY_SCOPE_AGENT);
                }
            }
            #pragma unroll
            for (int i = 0; i < 3; ++i) {
                u64t* dp = (u64t*)&Als[p][prow][pcolv[i]];
                dp[0] = ev[i][0]; dp[1] = ev[i][1];
            }
        }
        __syncthreads();  // C: Als[p] complete
        // ---- partner-ktile MFMA; init acc with own + x contributions ----
        v4f acc0 = accO0 + accX0;
        v4f acc1 = accO1 + accX1;
        #pragma unroll
        for (int i = 0; i < 12; ++i) {
            int ktp = i + ((i >= (s << 2)) ? 4 : 0);
            v8s a = *(const v8s*)((const uint16_t*)&Als[p][c][0] + ktp * 32 + q * 8);
            acc0 = __builtin_amdgcn_mfma_f32_16x16x32_bf16(a, Uf[0][i], acc0, 0, 0, 0);
            acc1 = __builtin_amdgcn_mfma_f32_16x16x32_bf16(a, Uf[1][i], acc1, 0, 0, 0);
        }
        // ---- stage x(t+1) -> xls[1-p] (write-window safe: last reader of
        //      xls[1-p] finished before t-1's F; readers of this data are
        //      at t+1's head, after this step's F). Overlaps MFMA exec. ----
        if (t + 1 < T_) {
            uint16_t* dp = &xls[1 - p][r0][c16];
            dp[0] = f2bf(xr0.x); dp[1] = f2bf(xr0.y); dp[2]  = f2bf(xr0.z); dp[3]  = f2bf(xr0.w);
            dp[4] = f2bf(xr1.x); dp[5] = f2bf(xr1.y); dp[6]  = f2bf(xr1.z); dp[7]  = f2bf(xr1.w);
            dp[8] = f2bf(xr2.x); dp[9] = f2bf(xr2.y); dp[10] = f2bf(xr2.z); dp[11] = f2bf(xr2.w);
            dp[12] = f2bf(xr3.x); dp[13] = f2bf(xr3.y); dp[14] = f2bf(xr3.z); dp[15] = f2bf(xr3.w);
        }
        // ---- epilogue: pre = acc + bias; tanh; tagged bf16 -> Als[1-p] ----
        const uint16_t tauw = (uint16_t)(((t + 1) >> 1) & 1);
        #pragma unroll
        for (int nt = 0; nt < 2; ++nt) {
            v4f av = nt ? acc1 : acc0;
            int jl = s * 128 + (2 * w + nt) * 16 + c;
            #pragma unroll
            for (int r = 0; r < 4; ++r) {
                float pre = av[r] + bias_r[nt];
                float ex = __expf(pre + pre);                           // e^{2x}
                float ct = 1.f - 2.f * __builtin_amdgcn_rcpf(ex + 1.f); // tanh
                float hn = sb * hold[nt][r] + sa * ct;
                hold[nt][r] = hn;
                Als[1 - p][q * 4 + r][jl] = (uint16_t)((f2bf(hn) & 0xFFFEu) | tauw);
            }
        }
        __syncthreads();  // F: Als[1-p] own region complete
        if (t + 1 < T_) {
            // ---- publish own chunk FIRST (partner's critical path) ----
            {
                const u64t* sp = (const u64t*)&Als[1 - p][orow][ocol];
                u64t o0 = sp[0], o1 = sp[1];
                u64t* pp = (u64t*)(Hbuf + (size_t)(1 - p) * (B_ * H_) + ooff);
                __hip_atomic_store(&pp[0], o0, __ATOMIC_RELAXED,
                                   __HIP_MEMORY_SCOPE_AGENT);
                __hip_atomic_store(&pp[1], o1, __ATOMIC_RELAXED,
                                   __HIP_MEMORY_SCOPE_AGENT);
            }
            // ---- own-ktile MFMA for t+1 — overlaps the LLC propagation ----
            accO0 = (v4f){0.f, 0.f, 0.f, 0.f};
            accO1 = (v4f){0.f, 0.f, 0.f, 0.f};
            #pragma unroll
            for (int i = 0; i < 4; ++i) {
                int kto = (s << 2) + i;
                v8s a = *(const v8s*)((const uint16_t*)&Als[1 - p][c][0] + kto * 32 + q * 8);
                accO0 = __builtin_amdgcn_mfma_f32_16x16x32_bf16(a, Uf[0][12 + i], accO0, 0, 0, 0);
                accO1 = __builtin_amdgcn_mfma_f32_16x16x32_bf16(a, Uf[1][12 + i], accO1, 0, 0, 0);
            }
            // ---- early-issue next poll loads (stale caught by tag check) ----
            const uint16_t* hbn = Hbuf + (size_t)(1 - p) * (B_ * H_);
            #pragma unroll
            for (int i = 0; i < 3; ++i) {
                const u64t* gp = (const u64t*)(hbn + poffv[i]);
                ev[i][0] = __hip_atomic_load(&gp[0], __ATOMIC_RELAXED,
                                             __HIP_MEMORY_SCOPE_AGENT);
                ev[i][1] = __hip_atomic_load(&gp[1], __ATOMIC_RELAXED,
                                             __HIP_MEMORY_SCOPE_AGENT);
            }
            // ---- x prefetch for t+2 (plain loads; LLC dedupes s-sharing) ----
            if (t + 2 < T_) {
                xr0 = *(const float4*)(xptr + 0);
                xr1 = *(const float4*)(xptr + 4);
                xr2 = *(const float4*)(xptr + 8);
                xr3 = *(const float4*)(xptr + 12);
                xptr += I_;
            }
        }
        // ---- out stores — plain (retire in local L2), off the chain ----
        #pragma unroll
        for (int nt = 0; nt < 2; ++nt) {
            int jg = s * 128 + (2 * w + nt) * 16 + c;
            #pragma unroll
            for (int r = 0; r < 4; ++r) {
                int bg = g * 16 + q * 4 + r;
                out[((size_t)bg * T_ + t) * H_ + jg] = hold[nt][r];
            }
        }
    }
}

extern "C" void kernel_launch(void* const* d_in, const int* in_sizes, int n_in,
                              void* d_out, int out_size, void* d_ws, size_t ws_size,
                              hipStream_t stream) {
    const float* x     = (const float*)d_in[0];
    const float* W     = (const float*)d_in[1];
    const float* U     = (const float*)d_in[2];
    const float* bias  = (const float*)d_in[3];
    const float* alpha = (const float*)d_in[4];
    const float* beta  = (const float*)d_in[5];
    float* out = (float*)d_out;

    uint16_t* Hbuf = (uint16_t*)d_ws;   // 128 KiB tagged bf16 (wxb eliminated)

    // Warm-up tag safety: parity 0 halves get LSB=0 (invalid at t'=2 which
    // expects tau=1), parity 1 halves get LSB=1 (invalid at t'=1, tau=0).
    hipMemsetAsync(Hbuf, 0x00, HHALF_BYTES, stream);
    hipMemsetAsync((char*)Hbuf + HHALF_BYTES, 0xFF, HHALF_BYTES, stream);

    rnn_scan<<<dim3(16), dim3(256), 0, stream>>>(
        x, W, U, bias, alpha, beta, out, Hbuf);
}

// Round 12
// 1239.953 us; speedup vs baseline: 1.1617x; 1.1617x over previous
//
#include <hip/hip_runtime.h>
#include <stdint.h>

// FastRNN: B=64, T=512, I=256, H=512, fp32.
// R18: scan reverted to R14 VERBATIM (best passing, 1076us); wx GEMM fused
//   into the SAME LAUNCH on the other 240 CUs (not into the scan timeline —
//   R17 proved the step loop has no slack: +1270cy/step).
//   One grid: blocks 0..15 = scan role (R14 exact), 16..4111 = gemm role.
//   Producer/consumer correctness via the session-proven tag idiom, applied
//   to wxb: gemm publishes wx with fp32-LSB|1 (<=1ulp) via agent-scope
//   atomic stores (LLC-visible; plain stores would sit in producer-XCD L2);
//   wxb memset to 0 (LSB=0=invalid) first; scan wx loads are agent-scope
//   atomic (L2-bypass so spins can't cache staleness) + check-reload at use.
//   Gemm blocks t-major (all t<64 first) so production leads consumption
//   (~2.1us/step). Dispatch-order pathology = slowdown only, never wrong
//   (tags+guard). 82KB LDS forces 1 block/CU: gemm never co-resides with
//   scan blocks (pipe isolation).

#define B_ 64
#define T_ 512
#define I_ 256
#define H_ 512
#define M_ (B_ * T_)  // 32768
#define NSCAN 16

#define WXB_BYTES  ((size_t)M_ * H_ * 4)       // 64 MiB fp32
#define HHALF_BYTES ((size_t)B_ * H_ * 2)      // 64 KiB bf16 per parity

typedef short v8s __attribute__((ext_vector_type(8)));
typedef float v4f __attribute__((ext_vector_type(4)));
typedef unsigned long long u64t;

__device__ __forceinline__ uint16_t f2bf(float x) {
    union { float f; uint32_t u; } v; v.f = x;
    return (uint16_t)((v.u + 0x7FFFu + ((v.u >> 16) & 1u)) >> 16);
}

__global__ __launch_bounds__(256, 1) void rnn_fused(
        const float* __restrict__ x, const float* __restrict__ W,
        const float* __restrict__ U, const float* __restrict__ bias,
        const float* __restrict__ alpha, const float* __restrict__ beta,
        float* __restrict__ out, float* __restrict__ wxb,
        uint16_t* __restrict__ Hbuf) {
    // 83968 B single allocation -> 1 block/CU for ALL roles.
    __shared__ __align__(16) uint16_t smem[41984];

    const int tid = threadIdx.x;
    const int lane = tid & 63;
    const int w = tid >> 6;
    const int q = lane >> 4, c = lane & 15;

    if (blockIdx.x >= NSCAN) {
        // ================= GEMM role: wxb = x@W + bias, tagged =============
        // t-major block order: gbid = t0*(64*8) + b*8 + n.
        const int gbid = (int)blockIdx.x - NSCAN;
        const int t0 = gbid >> 9, b = (gbid >> 3) & 63, n = gbid & 7;
        const int mbase = b * T_ + t0 * 64;   // m = b*T + t
        const int nbase = n * 64;
        uint16_t (*Asl)[40] = (uint16_t(*)[40])smem;          // 64x40 u16
        uint16_t* Bsl = smem + 64 * 40;                        // 4*64*8 u16

        v4f acc[4];
        #pragma unroll
        for (int i = 0; i < 4; ++i) acc[i] = (v4f){0.f, 0.f, 0.f, 0.f};

        for (int ks = 0; ks < I_; ks += 32) {
            {
                int row = tid >> 2, c4 = tid & 3;
                const float* gp = x + (size_t)(mbase + row) * I_ + ks + c4 * 8;
                float4 f0 = *(const float4*)gp;
                float4 f1 = *(const float4*)(gp + 4);
                uint16_t* dp = &Asl[row][c4 * 8];
                dp[0] = f2bf(f0.x); dp[1] = f2bf(f0.y); dp[2] = f2bf(f0.z); dp[3] = f2bf(f0.w);
                dp[4] = f2bf(f1.x); dp[5] = f2bf(f1.y); dp[6] = f2bf(f1.z); dp[7] = f2bf(f1.w);
            }
            {
                int nt = tid >> 6;
                const float* gp = W + (size_t)(ks + q * 8) * H_ + nbase + nt * 16 + c;
                union { v8s v; uint16_t u[8]; } pk;
                #pragma unroll
                for (int jj = 0; jj < 8; ++jj) pk.u[jj] = f2bf(gp[(size_t)jj * H_]);
                *(v8s*)&Bsl[(nt * 64 + lane) * 8] = pk.v;
            }
            __syncthreads();
            const v8s* Bf = (const v8s*)Bsl;
            v8s a = *(const v8s*)&Asl[w * 16 + c][q * 8];
            #pragma unroll
            for (int nt = 0; nt < 4; ++nt) {
                v8s bfr = Bf[nt * 64 + lane];
                acc[nt] = __builtin_amdgcn_mfma_f32_16x16x32_bf16(a, bfr, acc[nt], 0, 0, 0);
            }
            __syncthreads();
        }
        #pragma unroll
        for (int nt = 0; nt < 4; ++nt) {
            int j = nbase + nt * 16 + c;
            float bj = bias[j];
            #pragma unroll
            for (int r = 0; r < 4; ++r) {
                int m = mbase + w * 16 + q * 4 + r;
                union { float f; uint32_t u; } v; v.f = acc[nt][r] + bj;
                v.u |= 1u;   // valid-tag in fp32 mantissa LSB (<=1ulp)
                __hip_atomic_store((uint32_t*)&wxb[(size_t)m * H_ + j], v.u,
                                   __ATOMIC_RELAXED, __HIP_MEMORY_SCOPE_AGENT);
            }
        }
        return;
    }

    // ================= SCAN role: R14 verbatim + wx tag-poll ===============
    auto& Als = *(uint16_t(*)[2][16][520])smem;  // dbuf full-H state, +8 pad

    const int bid = blockIdx.x;       // 0..15
    const int g = bid >> 2, s = bid & 3;

    float sa, sb;
    { float a = alpha[0], b = beta[0];
      sa = 1.f / (1.f + __expf(-a)); sb = 1.f / (1.f + __expf(-b)); }

    // Loop-invariant U B-frags, [12 partner ktiles | 4 own ktiles] (R14).
    v8s Uf[2][16];
    #pragma unroll
    for (int nt = 0; nt < 2; ++nt) {
        int jg = s * 128 + (2 * w + nt) * 16 + c;
        #pragma unroll
        for (int slot = 0; slot < 16; ++slot) {
            int ktile = (slot < 12) ? (slot + ((slot >= (s << 2)) ? 4 : 0))
                                    : ((s << 2) + slot - 12);
            const float* gp = U + (size_t)(ktile * 32 + q * 8) * H_ + jg;
            union { v8s v; uint16_t u[8]; } pk;
            #pragma unroll
            for (int jj = 0; jj < 8; ++jj) pk.u[jj] = f2bf(gp[(size_t)jj * H_]);
            Uf[nt][slot] = pk.v;
        }
    }
    float hold[2][4];
    #pragma unroll
    for (int nt = 0; nt < 2; ++nt)
        #pragma unroll
        for (int r = 0; r < 4; ++r) hold[nt][r] = 0.f;

    // wx prefetch (one step ahead), agent-scope atomic (L2-bypass).
    float wxv[2][4], wxn[2][4];
    #pragma unroll
    for (int nt = 0; nt < 2; ++nt) {
        int jg = s * 128 + (2 * w + nt) * 16 + c;
        #pragma unroll
        for (int r = 0; r < 4; ++r) {
            int bg = g * 16 + q * 4 + r;
            uint32_t u = __hip_atomic_load(
                (const uint32_t*)&wxb[((size_t)bg * T_ + 0) * H_ + jg],
                __ATOMIC_RELAXED, __HIP_MEMORY_SCOPE_AGENT);
            wxn[nt][r] = __uint_as_float(u);
        }
    }

    // Partner poll mapping (R14): 3 partner slices, 16B chunk per thread.
    const int prow = tid >> 4;
    size_t poffv[3];
    int pcolv[3];
    #pragma unroll
    for (int i = 0; i < 3; ++i) {
        int sp = i + ((i >= s) ? 1 : 0);
        pcolv[i] = sp * 128 + (tid & 15) * 8;
        poffv[i] = ((size_t)(g * 16 + prow)) * H_ + pcolv[i];
    }
    const int orow = tid >> 4;
    const int ocol = s * 128 + (tid & 15) * 8;
    const size_t ooff = ((size_t)(g * 16 + orow)) * H_ + ocol;

    // Zero ALL of Als[0] (h_0 = 0): 2048 u64s, 8 per thread.
    #pragma unroll
    for (int u = 0; u < 8; ++u)
        *((u64t*)&Als[0][tid >> 4][0] + (tid & 15) * 8 + u) = 0;

    u64t ev[3][2];
    v4f accO0 = (v4f){0.f, 0.f, 0.f, 0.f};
    v4f accO1 = (v4f){0.f, 0.f, 0.f, 0.f};

    for (int t = 0; t < T_; ++t) {
        const int p = t & 1;
        // rotate wx prefetch buffer
        #pragma unroll
        for (int nt = 0; nt < 2; ++nt)
            #pragma unroll
            for (int r = 0; r < 4; ++r) wxv[nt][r] = wxn[nt][r];

        // ---- poll 3 partner h slices into Als[p] (R14 exact) ----
        if (t > 0) {
            const uint16_t* hbp = Hbuf + (size_t)p * (B_ * H_);
            const u64t lsb = 0x0001000100010001ull;
            const u64t want = ((t >> 1) & 1) ? lsb : 0ull;
            for (int guard = 0; guard < (1 << 20); ++guard) {
                u64t xx = (ev[0][0] ^ want) | (ev[0][1] ^ want)
                        | (ev[1][0] ^ want) | (ev[1][1] ^ want)
                        | (ev[2][0] ^ want) | (ev[2][1] ^ want);
                if (!(xx & lsb)) break;
                #pragma unroll
                for (int i = 0; i < 3; ++i) {
                    const u64t* gp = (const u64t*)(hbp + poffv[i]);
                    ev[i][0] = __hip_atomic_load(&gp[0], __ATOMIC_RELAXED,
                                                 __HIP_MEMORY_SCOPE_AGENT);
                    ev[i][1] = __hip_atomic_load(&gp[1], __ATOMIC_RELAXED,
                                                 __HIP_MEMORY_SCOPE_AGENT);
                }
            }
            #pragma unroll
            for (int i = 0; i < 3; ++i) {
                u64t* dp = (u64t*)&Als[p][prow][pcolv[i]];
                dp[0] = ev[i][0]; dp[1] = ev[i][1];
            }
        }
        __syncthreads();  // C: Als[p] complete
        // ---- partner-ktile MFMA (12 ktiles); own 4 done last tail ----
        v4f acc0 = accO0;
        v4f acc1 = accO1;
        #pragma unroll
        for (int i = 0; i < 12; ++i) {
            int ktp = i + ((i >= (s << 2)) ? 4 : 0);
            v8s a = *(const v8s*)((const uint16_t*)&Als[p][c][0] + ktp * 32 + q * 8);
            acc0 = __builtin_amdgcn_mfma_f32_16x16x32_bf16(a, Uf[0][i], acc0, 0, 0, 0);
            acc1 = __builtin_amdgcn_mfma_f32_16x16x32_bf16(a, Uf[1][i], acc1, 0, 0, 0);
        }
        // ---- wx validity check (tags); reload only until gemm catches up
        //      (steady state: 8 v_and + 1 branch, no reload) ----
        {
            for (int guard = 0; guard < (1 << 20); ++guard) {
                uint32_t andv = 0xFFFFFFFFu;
                #pragma unroll
                for (int nt = 0; nt < 2; ++nt)
                    #pragma unroll
                    for (int r = 0; r < 4; ++r)
                        andv &= __float_as_uint(wxv[nt][r]);
                if (andv & 1u) break;
                #pragma unroll
                for (int nt = 0; nt < 2; ++nt) {
                    int jg = s * 128 + (2 * w + nt) * 16 + c;
                    #pragma unroll
                    for (int r = 0; r < 4; ++r) {
                        int bg = g * 16 + q * 4 + r;
                        uint32_t u = __hip_atomic_load(
                            (const uint32_t*)&wxb[((size_t)bg * T_ + t) * H_ + jg],
                            __ATOMIC_RELAXED, __HIP_MEMORY_SCOPE_AGENT);
                        wxv[nt][r] = __uint_as_float(u);
                    }
                }
            }
        }
        // ---- epilogue: tagged bf16 h -> Als[1-p] own region (R14) ----
        const uint16_t tauw = (uint16_t)(((t + 1) >> 1) & 1);
        #pragma unroll
        for (int nt = 0; nt < 2; ++nt) {
            v4f av = nt ? acc1 : acc0;
            int jl = s * 128 + (2 * w + nt) * 16 + c;
            #pragma unroll
            for (int r = 0; r < 4; ++r) {
                float pre = av[r] + wxv[nt][r];
                float ex = __expf(pre + pre);                           // e^{2x}
                float ct = 1.f - 2.f * __builtin_amdgcn_rcpf(ex + 1.f); // tanh
                float hn = sb * hold[nt][r] + sa * ct;
                hold[nt][r] = hn;
                Als[1 - p][q * 4 + r][jl] = (uint16_t)((f2bf(hn) & 0xFFFEu) | tauw);
            }
        }
        __syncthreads();  // F: Als[1-p] own region complete
        if (t + 1 < T_) {
            // ---- publish own chunk FIRST (partner's critical path) ----
            {
                const u64t* sp = (const u64t*)&Als[1 - p][orow][ocol];
                u64t o0 = sp[0], o1 = sp[1];
                u64t* pp = (u64t*)(Hbuf + (size_t)(1 - p) * (B_ * H_) + ooff);
                __hip_atomic_store(&pp[0], o0, __ATOMIC_RELAXED,
                                   __HIP_MEMORY_SCOPE_AGENT);
                __hip_atomic_store(&pp[1], o1, __ATOMIC_RELAXED,
                                   __HIP_MEMORY_SCOPE_AGENT);
            }
            // ---- own-ktile MFMA for t+1 — overlaps LLC propagation ----
            accO0 = (v4f){0.f, 0.f, 0.f, 0.f};
            accO1 = (v4f){0.f, 0.f, 0.f, 0.f};
            #pragma unroll
            for (int i = 0; i < 4; ++i) {
                int kto = (s << 2) + i;
                v8s a = *(const v8s*)((const uint16_t*)&Als[1 - p][c][0] + kto * 32 + q * 8);
                accO0 = __builtin_amdgcn_mfma_f32_16x16x32_bf16(a, Uf[0][12 + i], accO0, 0, 0, 0);
                accO1 = __builtin_amdgcn_mfma_f32_16x16x32_bf16(a, Uf[1][12 + i], accO1, 0, 0, 0);
            }
            // ---- wx prefetch for t+1 (R14 tail position) ----
            #pragma unroll
            for (int nt = 0; nt < 2; ++nt) {
                int jg = s * 128 + (2 * w + nt) * 16 + c;
                #pragma unroll
                for (int r = 0; r < 4; ++r) {
                    int bg = g * 16 + q * 4 + r;
                    uint32_t u = __hip_atomic_load(
                        (const uint32_t*)&wxb[((size_t)bg * T_ + (t + 1)) * H_ + jg],
                        __ATOMIC_RELAXED, __HIP_MEMORY_SCOPE_AGENT);
                    wxn[nt][r] = __uint_as_float(u);
                }
            }
            // ---- early-issue next h poll loads ----
            const uint16_t* hbn = Hbuf + (size_t)(1 - p) * (B_ * H_);
            #pragma unroll
            for (int i = 0; i < 3; ++i) {
                const u64t* gp = (const u64t*)(hbn + poffv[i]);
                ev[i][0] = __hip_atomic_load(&gp[0], __ATOMIC_RELAXED,
                                             __HIP_MEMORY_SCOPE_AGENT);
                ev[i][1] = __hip_atomic_load(&gp[1], __ATOMIC_RELAXED,
                                             __HIP_MEMORY_SCOPE_AGENT);
            }
        }
        // ---- out stores — plain, off the chain ----
        #pragma unroll
        for (int nt = 0; nt < 2; ++nt) {
            int jg = s * 128 + (2 * w + nt) * 16 + c;
            #pragma unroll
            for (int r = 0; r < 4; ++r) {
                int bg = g * 16 + q * 4 + r;
                out[((size_t)bg * T_ + t) * H_ + jg] = hold[nt][r];
            }
        }
    }
}

extern "C" void kernel_launch(void* const* d_in, const int* in_sizes, int n_in,
                              void* d_out, int out_size, void* d_ws, size_t ws_size,
                              hipStream_t stream) {
    const float* x     = (const float*)d_in[0];
    const float* W     = (const float*)d_in[1];
    const float* U     = (const float*)d_in[2];
    const float* bias  = (const float*)d_in[3];
    const float* alpha = (const float*)d_in[4];
    const float* beta  = (const float*)d_in[5];
    float* out = (float*)d_out;

    char* ws = (char*)d_ws;
    float* wxb = (float*)ws;                                  // 64 MiB, tagged fp32
    uint16_t* Hbuf = (uint16_t*)(ws + WXB_BYTES);             // 128 KiB tagged bf16

    // wxb invalid (LSB=0) until gemm role writes it (LSB=1).
    hipMemsetAsync(wxb, 0x00, WXB_BYTES, stream);
    // Warm-up tag safety for h exchange (R6 scheme).
    hipMemsetAsync(Hbuf, 0x00, HHALF_BYTES, stream);
    hipMemsetAsync((char*)Hbuf + HHALF_BYTES, 0xFF, HHALF_BYTES, stream);

    rnn_fused<<<dim3(NSCAN + (M_ / 64) * (H_ / 64)), dim3(256), 0, stream>>>(
        x, W, U, bias, alpha, beta, out, wxb, Hbuf);
}

// Round 13
// 1221.184 us; speedup vs baseline: 1.1795x; 1.0154x over previous
//
#include <hip/hip_runtime.h>
#include <stdint.h>

// FastRNN: B=64, T=512, I=256, H=512, fp32.
// R19 = R18's same-launch fusion with the wxb tag protocol replaced by a
//   counter handshake (the two R18 regressions were both tag-induced):
//   - gemm role: wxb via PLAIN stores (R14 K1 epilogue exact) ->
//     __syncthreads (drains vmcnt; stores in L2) -> thread0
//     fetch_add(&cnt[t0],1,RELEASE,AGENT) (buffer_wbl2: L2->LLC flush).
//   - scan role: R14 VERBATIM (1076us), wx loads back to plain
//     nontemporal; gates each 64-step chunk ONCE on cnt[k]==512 with a
//     relaxed spin + one ACQUIRE load (buffer_inv -> subsequent plain
//     cacheable loads are fresh, incl. across graph replays). Release
//     sequence over the RMW chain covers all 512 producer blocks.
//   - memset: 64 MiB wxb memset GONE (only 32B counters + Hbuf).
//   t-major gemm block order keeps production ~8x ahead of consumption;
//   counters guarantee correctness under ANY dispatch order (slow only).
//   82KB LDS keeps 1 block/CU: gemm never co-resides with scan blocks.

#define B_ 64
#define T_ 512
#define I_ 256
#define H_ 512
#define M_ (B_ * T_)  // 32768
#define NSCAN 16

#define WXB_BYTES  ((size_t)M_ * H_ * 4)       // 64 MiB fp32
#define HHALF_BYTES ((size_t)B_ * H_ * 2)      // 64 KiB bf16 per parity

typedef short v8s __attribute__((ext_vector_type(8)));
typedef float v4f __attribute__((ext_vector_type(4)));
typedef unsigned long long u64t;

__device__ __forceinline__ uint16_t f2bf(float x) {
    union { float f; uint32_t u; } v; v.f = x;
    return (uint16_t)((v.u + 0x7FFFu + ((v.u >> 16) & 1u)) >> 16);
}

__device__ __forceinline__ void gate_chunk(const uint32_t* cnt, int k) {
    // Relaxed spin (no cache-maintenance per iteration), then ONE acquire
    // load: buffer_inv makes subsequent plain loads observe LLC-fresh data.
    for (int gd = 0; gd < (1 << 22); ++gd) {
        uint32_t v = __hip_atomic_load(&cnt[k], __ATOMIC_RELAXED,
                                       __HIP_MEMORY_SCOPE_AGENT);
        if (v >= 512u) break;
    }
    (void)__hip_atomic_load(&cnt[k], __ATOMIC_ACQUIRE,
                            __HIP_MEMORY_SCOPE_AGENT);
}

__global__ __launch_bounds__(256, 1) void rnn_fused(
        const float* __restrict__ x, const float* __restrict__ W,
        const float* __restrict__ U, const float* __restrict__ bias,
        const float* __restrict__ alpha, const float* __restrict__ beta,
        float* __restrict__ out, float* __restrict__ wxb,
        uint16_t* __restrict__ Hbuf, uint32_t* __restrict__ cnt) {
    // 83968 B single allocation -> 1 block/CU for ALL roles.
    __shared__ __align__(16) uint16_t smem[41984];

    const int tid = threadIdx.x;
    const int lane = tid & 63;
    const int w = tid >> 6;
    const int q = lane >> 4, c = lane & 15;

    if (blockIdx.x >= NSCAN) {
        // ================= GEMM role: wxb = x@W + bias ====================
        // t-major block order: gbid = t0*(64*8) + b*8 + n.
        const int gbid = (int)blockIdx.x - NSCAN;
        const int t0 = gbid >> 9, b = (gbid >> 3) & 63, n = gbid & 7;
        const int mbase = b * T_ + t0 * 64;   // m = b*T + t
        const int nbase = n * 64;
        uint16_t (*Asl)[40] = (uint16_t(*)[40])smem;          // 64x40 u16
        uint16_t* Bsl = smem + 64 * 40;                        // 4*64*8 u16

        v4f acc[4];
        #pragma unroll
        for (int i = 0; i < 4; ++i) acc[i] = (v4f){0.f, 0.f, 0.f, 0.f};

        for (int ks = 0; ks < I_; ks += 32) {
            {
                int row = tid >> 2, c4 = tid & 3;
                const float* gp = x + (size_t)(mbase + row) * I_ + ks + c4 * 8;
                float4 f0 = *(const float4*)gp;
                float4 f1 = *(const float4*)(gp + 4);
                uint16_t* dp = &Asl[row][c4 * 8];
                dp[0] = f2bf(f0.x); dp[1] = f2bf(f0.y); dp[2] = f2bf(f0.z); dp[3] = f2bf(f0.w);
                dp[4] = f2bf(f1.x); dp[5] = f2bf(f1.y); dp[6] = f2bf(f1.z); dp[7] = f2bf(f1.w);
            }
            {
                int nt = tid >> 6;
                const float* gp = W + (size_t)(ks + q * 8) * H_ + nbase + nt * 16 + c;
                union { v8s v; uint16_t u[8]; } pk;
                #pragma unroll
                for (int jj = 0; jj < 8; ++jj) pk.u[jj] = f2bf(gp[(size_t)jj * H_]);
                *(v8s*)&Bsl[(nt * 64 + lane) * 8] = pk.v;
            }
            __syncthreads();
            const v8s* Bf = (const v8s*)Bsl;
            v8s a = *(const v8s*)&Asl[w * 16 + c][q * 8];
            #pragma unroll
            for (int nt = 0; nt < 4; ++nt) {
                v8s bfr = Bf[nt * 64 + lane];
                acc[nt] = __builtin_amdgcn_mfma_f32_16x16x32_bf16(a, bfr, acc[nt], 0, 0, 0);
            }
            __syncthreads();
        }
        #pragma unroll
        for (int nt = 0; nt < 4; ++nt) {
            int j = nbase + nt * 16 + c;
            float bj = bias[j];
            #pragma unroll
            for (int r = 0; r < 4; ++r) {
                int m = mbase + w * 16 + q * 4 + r;
                wxb[(size_t)m * H_ + j] = acc[nt][r] + bj;   // plain store
            }
        }
        __syncthreads();   // all threads' stores drained (vmcnt 0) into L2
        if (tid == 0)      // release: buffer_wbl2 flushes L2 -> LLC first
            __hip_atomic_fetch_add(&cnt[t0], 1u, __ATOMIC_RELEASE,
                                   __HIP_MEMORY_SCOPE_AGENT);
        return;
    }

    // ================= SCAN role: R14 verbatim + chunk gates ==============
    auto& Als = *(uint16_t(*)[2][16][520])smem;  // dbuf full-H state, +8 pad

    const int bid = blockIdx.x;       // 0..15
    const int g = bid >> 2, s = bid & 3;

    float sa, sb;
    { float a = alpha[0], b = beta[0];
      sa = 1.f / (1.f + __expf(-a)); sb = 1.f / (1.f + __expf(-b)); }

    // Loop-invariant U B-frags, [12 partner ktiles | 4 own ktiles] (R14).
    v8s Uf[2][16];
    #pragma unroll
    for (int nt = 0; nt < 2; ++nt) {
        int jg = s * 128 + (2 * w + nt) * 16 + c;
        #pragma unroll
        for (int slot = 0; slot < 16; ++slot) {
            int ktile = (slot < 12) ? (slot + ((slot >= (s << 2)) ? 4 : 0))
                                    : ((s << 2) + slot - 12);
            const float* gp = U + (size_t)(ktile * 32 + q * 8) * H_ + jg;
            union { v8s v; uint16_t u[8]; } pk;
            #pragma unroll
            for (int jj = 0; jj < 8; ++jj) pk.u[jj] = f2bf(gp[(size_t)jj * H_]);
            Uf[nt][slot] = pk.v;
        }
    }
    float hold[2][4];
    #pragma unroll
    for (int nt = 0; nt < 2; ++nt)
        #pragma unroll
        for (int r = 0; r < 4; ++r) hold[nt][r] = 0.f;

    // Gate chunk 0, then wx prefetch (plain nontemporal — R14 exact).
    gate_chunk(cnt, 0);
    float wxv[2][4], wxn[2][4];
    #pragma unroll
    for (int nt = 0; nt < 2; ++nt) {
        int jg = s * 128 + (2 * w + nt) * 16 + c;
        #pragma unroll
        for (int r = 0; r < 4; ++r) {
            int bg = g * 16 + q * 4 + r;
            wxn[nt][r] = __builtin_nontemporal_load(
                &wxb[((size_t)bg * T_ + 0) * H_ + jg]);
        }
    }

    // Partner poll mapping (R14): 3 partner slices, 16B chunk per thread.
    const int prow = tid >> 4;
    size_t poffv[3];
    int pcolv[3];
    #pragma unroll
    for (int i = 0; i < 3; ++i) {
        int sp = i + ((i >= s) ? 1 : 0);
        pcolv[i] = sp * 128 + (tid & 15) * 8;
        poffv[i] = ((size_t)(g * 16 + prow)) * H_ + pcolv[i];
    }
    const int orow = tid >> 4;
    const int ocol = s * 128 + (tid & 15) * 8;
    const size_t ooff = ((size_t)(g * 16 + orow)) * H_ + ocol;

    // Zero ALL of Als[0] (h_0 = 0): 2048 u64s, 8 per thread.
    #pragma unroll
    for (int u = 0; u < 8; ++u)
        *((u64t*)&Als[0][tid >> 4][0] + (tid & 15) * 8 + u) = 0;

    u64t ev[3][2];
    v4f accO0 = (v4f){0.f, 0.f, 0.f, 0.f};
    v4f accO1 = (v4f){0.f, 0.f, 0.f, 0.f};

    for (int t = 0; t < T_; ++t) {
        const int p = t & 1;
        // rotate wx prefetch buffer (loads are a full step old -> retired)
        #pragma unroll
        for (int nt = 0; nt < 2; ++nt)
            #pragma unroll
            for (int r = 0; r < 4; ++r) wxv[nt][r] = wxn[nt][r];

        // ---- poll 3 partner h slices into Als[p] (R14 exact) ----
        if (t > 0) {
            const uint16_t* hbp = Hbuf + (size_t)p * (B_ * H_);
            const u64t lsb = 0x0001000100010001ull;
            const u64t want = ((t >> 1) & 1) ? lsb : 0ull;
            for (int guard = 0; guard < (1 << 20); ++guard) {
                u64t xx = (ev[0][0] ^ want) | (ev[0][1] ^ want)
                        | (ev[1][0] ^ want) | (ev[1][1] ^ want)
                        | (ev[2][0] ^ want) | (ev[2][1] ^ want);
                if (!(xx & lsb)) break;
                #pragma unroll
                for (int i = 0; i < 3; ++i) {
                    const u64t* gp = (const u64t*)(hbp + poffv[i]);
                    ev[i][0] = __hip_atomic_load(&gp[0], __ATOMIC_RELAXED,
                                                 __HIP_MEMORY_SCOPE_AGENT);
                    ev[i][1] = __hip_atomic_load(&gp[1], __ATOMIC_RELAXED,
                                                 __HIP_MEMORY_SCOPE_AGENT);
                }
            }
            #pragma unroll
            for (int i = 0; i < 3; ++i) {
                u64t* dp = (u64t*)&Als[p][prow][pcolv[i]];
                dp[0] = ev[i][0]; dp[1] = ev[i][1];
            }
        }
        __syncthreads();  // C: Als[p] complete
        // ---- partner-ktile MFMA (12 ktiles); own 4 done last tail ----
        v4f acc0 = accO0;
        v4f acc1 = accO1;
        #pragma unroll
        for (int i = 0; i < 12; ++i) {
            int ktp = i + ((i >= (s << 2)) ? 4 : 0);
            v8s a = *(const v8s*)((const uint16_t*)&Als[p][c][0] + ktp * 32 + q * 8);
            acc0 = __builtin_amdgcn_mfma_f32_16x16x32_bf16(a, Uf[0][i], acc0, 0, 0, 0);
            acc1 = __builtin_amdgcn_mfma_f32_16x16x32_bf16(a, Uf[1][i], acc1, 0, 0, 0);
        }
        // ---- epilogue: tagged bf16 h -> Als[1-p] own region (R14) ----
        const uint16_t tauw = (uint16_t)(((t + 1) >> 1) & 1);
        #pragma unroll
        for (int nt = 0; nt < 2; ++nt) {
            v4f av = nt ? acc1 : acc0;
            int jl = s * 128 + (2 * w + nt) * 16 + c;
            #pragma unroll
            for (int r = 0; r < 4; ++r) {
                float pre = av[r] + wxv[nt][r];
                float ex = __expf(pre + pre);                           // e^{2x}
                float ct = 1.f - 2.f * __builtin_amdgcn_rcpf(ex + 1.f); // tanh
                float hn = sb * hold[nt][r] + sa * ct;
                hold[nt][r] = hn;
                Als[1 - p][q * 4 + r][jl] = (uint16_t)((f2bf(hn) & 0xFFFEu) | tauw);
            }
        }
        __syncthreads();  // F: Als[1-p] own region complete
        if (t + 1 < T_) {
            // ---- publish own chunk FIRST (partner's critical path) ----
            {
                const u64t* sp = (const u64t*)&Als[1 - p][orow][ocol];
                u64t o0 = sp[0], o1 = sp[1];
                u64t* pp = (u64t*)(Hbuf + (size_t)(1 - p) * (B_ * H_) + ooff);
                __hip_atomic_store(&pp[0], o0, __ATOMIC_RELAXED,
                                   __HIP_MEMORY_SCOPE_AGENT);
                __hip_atomic_store(&pp[1], o1, __ATOMIC_RELAXED,
                                   __HIP_MEMORY_SCOPE_AGENT);
            }
            // ---- own-ktile MFMA for t+1 — overlaps LLC propagation ----
            accO0 = (v4f){0.f, 0.f, 0.f, 0.f};
            accO1 = (v4f){0.f, 0.f, 0.f, 0.f};
            #pragma unroll
            for (int i = 0; i < 4; ++i) {
                int kto = (s << 2) + i;
                v8s a = *(const v8s*)((const uint16_t*)&Als[1 - p][c][0] + kto * 32 + q * 8);
                accO0 = __builtin_amdgcn_mfma_f32_16x16x32_bf16(a, Uf[0][12 + i], accO0, 0, 0, 0);
                accO1 = __builtin_amdgcn_mfma_f32_16x16x32_bf16(a, Uf[1][12 + i], accO1, 0, 0, 0);
            }
            // ---- chunk gate (8 times total; no-op in steady state) ----
            if (((t + 1) & 63) == 0) gate_chunk(cnt, (t + 1) >> 6);
            // ---- wx prefetch for t+1 (R14 exact: plain nontemporal) ----
            #pragma unroll
            for (int nt = 0; nt < 2; ++nt) {
                int jg = s * 128 + (2 * w + nt) * 16 + c;
                #pragma unroll
                for (int r = 0; r < 4; ++r) {
                    int bg = g * 16 + q * 4 + r;
                    wxn[nt][r] = __builtin_nontemporal_load(
                        &wxb[((size_t)bg * T_ + (t + 1)) * H_ + jg]);
                }
            }
            // ---- early-issue next h poll loads (R14 exact) ----
            const uint16_t* hbn = Hbuf + (size_t)(1 - p) * (B_ * H_);
            #pragma unroll
            for (int i = 0; i < 3; ++i) {
                const u64t* gp = (const u64t*)(hbn + poffv[i]);
                ev[i][0] = __hip_atomic_load(&gp[0], __ATOMIC_RELAXED,
                                             __HIP_MEMORY_SCOPE_AGENT);
                ev[i][1] = __hip_atomic_load(&gp[1], __ATOMIC_RELAXED,
                                             __HIP_MEMORY_SCOPE_AGENT);
            }
        }
        // ---- out stores — plain, off the chain ----
        #pragma unroll
        for (int nt = 0; nt < 2; ++nt) {
            int jg = s * 128 + (2 * w + nt) * 16 + c;
            #pragma unroll
            for (int r = 0; r < 4; ++r) {
                int bg = g * 16 + q * 4 + r;
                out[((size_t)bg * T_ + t) * H_ + jg] = hold[nt][r];
            }
        }
    }
}

extern "C" void kernel_launch(void* const* d_in, const int* in_sizes, int n_in,
                              void* d_out, int out_size, void* d_ws, size_t ws_size,
                              hipStream_t stream) {
    const float* x     = (const float*)d_in[0];
    const float* W     = (const float*)d_in[1];
    const float* U     = (const float*)d_in[2];
    const float* bias  = (const float*)d_in[3];
    const float* alpha = (const float*)d_in[4];
    const float* beta  = (const float*)d_in[5];
    float* out = (float*)d_out;

    char* ws = (char*)d_ws;
    float* wxb = (float*)ws;                                  // 64 MiB (no memset!)
    uint16_t* Hbuf = (uint16_t*)(ws + WXB_BYTES);             // 128 KiB tagged bf16
    uint32_t* cnt = (uint32_t*)(ws + WXB_BYTES + 2 * HHALF_BYTES);  // 8 u32

    // h-exchange warm-up tag safety (R6 scheme) + chunk counters to 0.
    hipMemsetAsync(Hbuf, 0x00, HHALF_BYTES, stream);
    hipMemsetAsync((char*)Hbuf + HHALF_BYTES, 0xFF, HHALF_BYTES, stream);
    hipMemsetAsync(cnt, 0x00, 8 * sizeof(uint32_t), stream);

    rnn_fused<<<dim3(NSCAN + (M_ / 64) * (H_ / 64)), dim3(256), 0, stream>>>(
        x, W, U, bias, alpha, beta, out, wxb, Hbuf, cnt);
}

// Round 14
// 1140.033 us; speedup vs baseline: 1.2635x; 1.0712x over previous
//
#include <hip/hip_runtime.h>
#include <stdint.h>

// FastRNN: B=64, T=512, I=256, H=512, fp32.
//   K1: wx = x @ W + bias  (bf16 MFMA GEMM) — R14 unchanged.
//   K2: h_t = sb*h + sa*tanh(wx_t + h @ U).
// R20 = R14 (best, 1165us total / 1076us scan) + register-direct publish
//   moved BEFORE barrier F. Mechanism: step time is quantized in ~900cy
//   spin-round units (head tag-check retries cost one L2-bypass LLC RT
//   each); publishing earlier shaves a round on a fraction of steps.
//   Change: Hbuf goes column-major-within-group (off = g*8192 + col*16 +
//   row, u16 units) so a u64 chunk = rows q*4..+3 of ONE col = one lane's
//   hold[nt][0..3] — packed from regs in the epilogue, stored pre-F with
//   zero cross-lane ops; 64-lane store = 512B contiguous. Consumer poll
//   loads become adjacent-u64 coalesced; staging into Als = 24 scalar b16
//   writes (2-way bank aliasing = free, m136). Happens-before chain for
//   ABA (publish after poll-C + epilogue) unchanged; tags/parity/memset
//   semantics identical to R14. Fusion (R18/R19) abandoned: contention
//   +75us > serial savings; two-kernel form restored.

#define B_ 64
#define T_ 512
#define I_ 256
#define H_ 512
#define M_ (B_ * T_)  // 32768

#define WXB_BYTES  ((size_t)M_ * H_ * 4)       // 64 MiB fp32
#define HHALF_BYTES ((size_t)B_ * H_ * 2)      // 64 KiB bf16 per parity
#define GSTRIDE (16 * H_)                      // u16 per batch-group slab

typedef short v8s __attribute__((ext_vector_type(8)));
typedef float v4f __attribute__((ext_vector_type(4)));
typedef unsigned long long u64t;

__device__ __forceinline__ uint16_t f2bf(float x) {
    union { float f; uint32_t u; } v; v.f = x;
    return (uint16_t)((v.u + 0x7FFFu + ((v.u >> 16) & 1u)) >> 16);
}

// --------------- K1: wxb[m][j] = x[m][:] @ W[:][j] + bias[j] ----------------
__global__ __launch_bounds__(256) void wx_gemm(
        const float* __restrict__ x, const float* __restrict__ W,
        const float* __restrict__ bias, float* __restrict__ wxb) {
    __shared__ uint16_t Asl[64][40];
    __shared__ uint16_t Bsl[4 * 64 * 8];

    const int tid = threadIdx.x;
    const int lane = tid & 63;
    const int w = tid >> 6;
    const int q = lane >> 4, c = lane & 15;
    const int mbase = (int)(blockIdx.x >> 3) * 64;
    const int nbase = (int)(blockIdx.x & 7) * 64;

    v4f acc[4];
    #pragma unroll
    for (int i = 0; i < 4; ++i) acc[i] = (v4f){0.f, 0.f, 0.f, 0.f};

    for (int ks = 0; ks < I_; ks += 32) {
        {
            int row = tid >> 2, c4 = tid & 3;
            const float* gp = x + (size_t)(mbase + row) * I_ + ks + c4 * 8;
            float4 f0 = *(const float4*)gp;
            float4 f1 = *(const float4*)(gp + 4);
            uint16_t* dp = &Asl[row][c4 * 8];
            dp[0] = f2bf(f0.x); dp[1] = f2bf(f0.y); dp[2] = f2bf(f0.z); dp[3] = f2bf(f0.w);
            dp[4] = f2bf(f1.x); dp[5] = f2bf(f1.y); dp[6] = f2bf(f1.z); dp[7] = f2bf(f1.w);
        }
        {
            int nt = tid >> 6;
            const float* gp = W + (size_t)(ks + q * 8) * H_ + nbase + nt * 16 + c;
            union { v8s v; uint16_t u[8]; } pk;
            #pragma unroll
            for (int jj = 0; jj < 8; ++jj) pk.u[jj] = f2bf(gp[(size_t)jj * H_]);
            *(v8s*)&Bsl[(nt * 64 + lane) * 8] = pk.v;
        }
        __syncthreads();
        const v8s* Bf = (const v8s*)Bsl;
        v8s a = *(const v8s*)&Asl[w * 16 + c][q * 8];
        #pragma unroll
        for (int nt = 0; nt < 4; ++nt) {
            v8s b = Bf[nt * 64 + lane];
            acc[nt] = __builtin_amdgcn_mfma_f32_16x16x32_bf16(a, b, acc[nt], 0, 0, 0);
        }
        __syncthreads();
    }
    #pragma unroll
    for (int nt = 0; nt < 4; ++nt) {
        int j = nbase + nt * 16 + c;
        float bj = bias[j];
        #pragma unroll
        for (int r = 0; r < 4; ++r) {
            int m = mbase + w * 16 + q * 4 + r;
            wxb[(size_t)m * H_ + j] = acc[nt][r] + bj;
        }
    }
}

// --------------- K2: recurrent scan ----------------------------------------
__global__ __launch_bounds__(256, 1) void rnn_scan(
        const float* __restrict__ U, const float* __restrict__ wxb,
        const float* __restrict__ alpha, const float* __restrict__ beta,
        float* __restrict__ out, uint16_t* __restrict__ Hbuf) {
    __shared__ __align__(16) uint16_t Als[2][16][520];  // dbuf full-H state, +8 pad

    const int bid = blockIdx.x;       // 0..15
    const int g = bid >> 2, s = bid & 3;
    const int tid = threadIdx.x;      // 0..255
    const int lane = tid & 63;
    const int w = tid >> 6;           // wave 0..3
    const int q = lane >> 4, c = lane & 15;

    float sa, sb;
    { float a = alpha[0], b = beta[0];
      sa = 1.f / (1.f + __expf(-a)); sb = 1.f / (1.f + __expf(-b)); }

    // Loop-invariant U B-frags, [12 partner ktiles | 4 own ktiles] (R14).
    v8s Uf[2][16];
    #pragma unroll
    for (int nt = 0; nt < 2; ++nt) {
        int jg = s * 128 + (2 * w + nt) * 16 + c;
        #pragma unroll
        for (int slot = 0; slot < 16; ++slot) {
            int ktile = (slot < 12) ? (slot + ((slot >= (s << 2)) ? 4 : 0))
                                    : ((s << 2) + slot - 12);
            const float* gp = U + (size_t)(ktile * 32 + q * 8) * H_ + jg;
            union { v8s v; uint16_t u[8]; } pk;
            #pragma unroll
            for (int jj = 0; jj < 8; ++jj) pk.u[jj] = f2bf(gp[(size_t)jj * H_]);
            Uf[nt][slot] = pk.v;
        }
    }
    float hold[2][4];
    #pragma unroll
    for (int nt = 0; nt < 2; ++nt)
        #pragma unroll
        for (int r = 0; r < 4; ++r) hold[nt][r] = 0.f;

    // wx prefetch: one step ahead (R14 exact).
    float wxv[2][4], wxn[2][4];
    #pragma unroll
    for (int nt = 0; nt < 2; ++nt) {
        int jg = s * 128 + (2 * w + nt) * 16 + c;
        #pragma unroll
        for (int r = 0; r < 4; ++r) {
            int bg = g * 16 + q * 4 + r;
            wxn[nt][r] = __builtin_nontemporal_load(
                &wxb[((size_t)bg * T_ + 0) * H_ + jg]);
        }
    }

    // Col-major Hbuf: off(parity,g,col,row) = parity*B*H + g*GSTRIDE +
    // col*16 + row  (u16 units). Poll: thread owns u64 chunks 2*tid+k
    // (k=0,1) per partner slice; chunk u -> col = s'*128 + (u>>2),
    // rows (u&3)*4..+3. Adjacent threads = adjacent u64s (coalesced).
    size_t poff2[3][2];
    int pcol2[3][2], prw2[3][2];
    #pragma unroll
    for (int i = 0; i < 3; ++i) {
        int sp = i + ((i >= s) ? 1 : 0);
        #pragma unroll
        for (int k = 0; k < 2; ++k) {
            int u = tid * 2 + k;
            int col = sp * 128 + (u >> 2);
            int rq = u & 3;
            pcol2[i][k] = col;
            prw2[i][k] = rq * 4;
            poff2[i][k] = (size_t)g * GSTRIDE + (size_t)col * 16 + rq * 4;
        }
    }
    // Publish: thread's own 2 u64s = hold[nt][0..3] at col jl, rows q*4..+3.
    size_t ooff2[2];
    #pragma unroll
    for (int nt = 0; nt < 2; ++nt) {
        int jl = s * 128 + (2 * w + nt) * 16 + c;
        ooff2[nt] = (size_t)g * GSTRIDE + (size_t)jl * 16 + q * 4;
    }

    // Zero ALL of Als[0] (h_0 = 0): 2048 u64s, 8 per thread (R14).
    #pragma unroll
    for (int u = 0; u < 8; ++u)
        *((u64t*)&Als[0][tid >> 4][0] + (tid & 15) * 8 + u) = 0;

    u64t ev[3][2];                 // early-issued partner poll loads
    v4f accO0 = (v4f){0.f, 0.f, 0.f, 0.f};   // own-ktile contribution
    v4f accO1 = (v4f){0.f, 0.f, 0.f, 0.f};

    for (int t = 0; t < T_; ++t) {
        const int p = t & 1;
        // rotate wx prefetch buffer (loads a full step old -> retired)
        #pragma unroll
        for (int nt = 0; nt < 2; ++nt)
            #pragma unroll
            for (int r = 0; r < 4; ++r) wxv[nt][r] = wxn[nt][r];

        // ---- poll 3 partner slices (tag check-reload, R14 idiom) ----
        if (t > 0) {
            const uint16_t* hbp = Hbuf + (size_t)p * (B_ * H_);
            const u64t lsb = 0x0001000100010001ull;
            const u64t want = ((t >> 1) & 1) ? lsb : 0ull;
            for (int guard = 0; guard < (1 << 20); ++guard) {
                u64t xx = (ev[0][0] ^ want) | (ev[0][1] ^ want)
                        | (ev[1][0] ^ want) | (ev[1][1] ^ want)
                        | (ev[2][0] ^ want) | (ev[2][1] ^ want);
                if (!(xx & lsb)) break;
                #pragma unroll
                for (int i = 0; i < 3; ++i)
                    #pragma unroll
                    for (int k = 0; k < 2; ++k)
                        ev[i][k] = __hip_atomic_load(
                            (const u64t*)(hbp + poff2[i][k]),
                            __ATOMIC_RELAXED, __HIP_MEMORY_SCOPE_AGENT);
            }
            // stage into Als[p]: u64 = rows rq..rq+3 of one col (transpose
            // via 4 scalar b16 writes; 2-way bank aliasing = free)
            #pragma unroll
            for (int i = 0; i < 3; ++i)
                #pragma unroll
                for (int k = 0; k < 2; ++k) {
                    u64t v = ev[i][k];
                    int col = pcol2[i][k], rw = prw2[i][k];
                    Als[p][rw + 0][col] = (uint16_t)(v);
                    Als[p][rw + 1][col] = (uint16_t)(v >> 16);
                    Als[p][rw + 2][col] = (uint16_t)(v >> 32);
                    Als[p][rw + 3][col] = (uint16_t)(v >> 48);
                }
        }
        __syncthreads();  // C: Als[p] complete
        // ---- partner-ktile MFMA (12 ktiles); own 4 done last tail ----
        v4f acc0 = accO0;
        v4f acc1 = accO1;
        #pragma unroll
        for (int i = 0; i < 12; ++i) {
            int ktp = i + ((i >= (s << 2)) ? 4 : 0);
            v8s a = *(const v8s*)((const uint16_t*)&Als[p][c][0] + ktp * 32 + q * 8);
            acc0 = __builtin_amdgcn_mfma_f32_16x16x32_bf16(a, Uf[0][i], acc0, 0, 0, 0);
            acc1 = __builtin_amdgcn_mfma_f32_16x16x32_bf16(a, Uf[1][i], acc1, 0, 0, 0);
        }
        // ---- epilogue: fp32 state in regs; tagged bf16 -> Als[1-p] own
        //      region AND pack publish u64s from the same tagged values ----
        const uint16_t tauw = (uint16_t)(((t + 1) >> 1) & 1);
        u64t pub[2];
        #pragma unroll
        for (int nt = 0; nt < 2; ++nt) {
            v4f av = nt ? acc1 : acc0;
            int jl = s * 128 + (2 * w + nt) * 16 + c;
            u64t pk = 0;
            #pragma unroll
            for (int r = 0; r < 4; ++r) {
                float pre = av[r] + wxv[nt][r];
                float ex = __expf(pre + pre);                           // e^{2x}
                float ct = 1.f - 2.f * __builtin_amdgcn_rcpf(ex + 1.f); // tanh
                float hn = sb * hold[nt][r] + sa * ct;
                hold[nt][r] = hn;
                uint16_t tv = (uint16_t)((f2bf(hn) & 0xFFFEu) | tauw);
                Als[1 - p][q * 4 + r][jl] = tv;
                pk |= (u64t)tv << (16 * r);
            }
            pub[nt] = pk;
        }
        // ---- publish DIRECT FROM REGS, BEFORE barrier F (R20 change):
        //      ~300-400cy earlier on the partner's critical path. The
        //      happens-before chain (publish after poll-C + epilogue)
        //      is unchanged -> ABA safety identical to R14. ----
        if (t + 1 < T_) {
            uint16_t* hb1 = Hbuf + (size_t)(1 - p) * (B_ * H_);
            #pragma unroll
            for (int nt = 0; nt < 2; ++nt)
                __hip_atomic_store((u64t*)(hb1 + ooff2[nt]), pub[nt],
                                   __ATOMIC_RELAXED, __HIP_MEMORY_SCOPE_AGENT);
        }
        __syncthreads();  // F: Als[1-p] own region complete (for own-MFMA)
        if (t + 1 < T_) {
            // ---- own-ktile MFMA for t+1 — overlaps LLC propagation ----
            accO0 = (v4f){0.f, 0.f, 0.f, 0.f};
            accO1 = (v4f){0.f, 0.f, 0.f, 0.f};
            #pragma unroll
            for (int i = 0; i < 4; ++i) {
                int kto = (s << 2) + i;
                v8s a = *(const v8s*)((const uint16_t*)&Als[1 - p][c][0] + kto * 32 + q * 8);
                accO0 = __builtin_amdgcn_mfma_f32_16x16x32_bf16(a, Uf[0][12 + i], accO0, 0, 0, 0);
                accO1 = __builtin_amdgcn_mfma_f32_16x16x32_bf16(a, Uf[1][12 + i], accO1, 0, 0, 0);
            }
            // ---- wx prefetch for t+1 (R14 tail position) ----
            #pragma unroll
            for (int nt = 0; nt < 2; ++nt) {
                int jg = s * 128 + (2 * w + nt) * 16 + c;
                #pragma unroll
                for (int r = 0; r < 4; ++r) {
                    int bg = g * 16 + q * 4 + r;
                    wxn[nt][r] = __builtin_nontemporal_load(
                        &wxb[((size_t)bg * T_ + (t + 1)) * H_ + jg]);
                }
            }
            // ---- early-issue next poll loads (stale caught by tags) ----
            const uint16_t* hbn = Hbuf + (size_t)(1 - p) * (B_ * H_);
            #pragma unroll
            for (int i = 0; i < 3; ++i)
                #pragma unroll
                for (int k = 0; k < 2; ++k)
                    ev[i][k] = __hip_atomic_load(
                        (const u64t*)(hbn + poff2[i][k]),
                        __ATOMIC_RELAXED, __HIP_MEMORY_SCOPE_AGENT);
        }
        // ---- out stores — plain, off the chain ----
        #pragma unroll
        for (int nt = 0; nt < 2; ++nt) {
            int jg = s * 128 + (2 * w + nt) * 16 + c;
            #pragma unroll
            for (int r = 0; r < 4; ++r) {
                int bg = g * 16 + q * 4 + r;
                out[((size_t)bg * T_ + t) * H_ + jg] = hold[nt][r];
            }
        }
    }
}

extern "C" void kernel_launch(void* const* d_in, const int* in_sizes, int n_in,
                              void* d_out, int out_size, void* d_ws, size_t ws_size,
                              hipStream_t stream) {
    const float* x     = (const float*)d_in[0];
    const float* W     = (const float*)d_in[1];
    const float* U     = (const float*)d_in[2];
    const float* bias  = (const float*)d_in[3];
    const float* alpha = (const float*)d_in[4];
    const float* beta  = (const float*)d_in[5];
    float* out = (float*)d_out;

    char* ws = (char*)d_ws;
    float* wxb = (float*)ws;                                  // 64 MiB
    uint16_t* Hbuf = (uint16_t*)(ws + WXB_BYTES);             // 128 KiB tagged bf16

    // Warm-up tag safety: parity 0 halves get LSB=0 (invalid at t'=2 which
    // expects tau=1), parity 1 halves get LSB=1 (invalid at t'=1, tau=0).
    // Layout-agnostic (per-u16 patterns), so col-major change is covered.
    hipMemsetAsync(Hbuf, 0x00, HHALF_BYTES, stream);
    hipMemsetAsync((char*)Hbuf + HHALF_BYTES, 0xFF, HHALF_BYTES, stream);

    wx_gemm<<<dim3((M_ / 64) * (H_ / 64)), dim3(256), 0, stream>>>(x, W, bias, wxb);
    rnn_scan<<<dim3(16), dim3(256), 0, stream>>>(U, wxb, alpha, beta, out, Hbuf);
}